// Round 17
// baseline (159.128 us; speedup 1.0000x reference)
//
#include <hip/hip_runtime.h>

#define MAXP 1048576           // static pair bound (MAX_PAIRS)
#define NATOMS 8192
#define D2_CUT 0x1.8ffffep+4f  // fl(sqrt(s))<5  <=>  s < 25-2^-19
#define CINV 0.175f            // 7/40: 7^3=343 cells, width 5.714 > 5.0004 (conservative)
#define NCELL 343
#define CANDCAP 2048           // neighborhood atoms (mean 645)
#define ROWCAP 128             // atoms per cell (mean 24)
#define HITCAP 192             // hits per row (mean 56)

// d_ws: rowcnt[8192] ints at 0, rowoff[8192] ints at 8192 floats
#define W_ROWCNT 0
#define W_ROWOFF 8192

__device__ __forceinline__ float sq3_nc(float x, float y, float z) {
#pragma clang fp contract(off)
  float a = x * x;
  float b = y * y;
  float c = z * z;
  return (a + b) + c;
}

// mask per _pairwise_dist: sq_i + sq_j - 2*(x @ x.T); BLAS K=3 FMA chain (bit-exact r12-r15)
__device__ __forceinline__ float d2_gram(float xi, float yi, float zi, float sqi,
                                         float xj, float yj, float zj, float sqj) {
#pragma clang fp contract(off)
  float g = xi * xj;
  g = __builtin_fmaf(yi, yj, g);
  g = __builtin_fmaf(zi, zj, g);
  float t = sqi + sqj;
  float d2 = t - 2.0f * g;
  return d2;
}

__device__ __forceinline__ float d2_direct(float xi, float yi, float zi,
                                           float xj, float yj, float zj) {
#pragma clang fp contract(off)
  float dx = xj - xi;
  float dy = yj - yi;
  float dz = zj - zi;
  float a = dx * dx;
  float b = dy * dy;
  float c = dz * dz;
  return (a + b) + c;
}

__device__ __forceinline__ int cellco(float v) {
  int c = (int)(v * CINV);
  return c < 0 ? 0 : (c > 6 ? 6 : c);
}

// K1: per-cell block: zero d_out slice + gather candidates/rows + count
__global__ __launch_bounds__(256) void nl_count(const float* __restrict__ pos,
                                                float* __restrict__ out,
                                                float* __restrict__ ws) {
  __shared__ float4 cand[CANDCAP];
  __shared__ int cj[CANDCAP];
  __shared__ int rows[ROWCAP];
  __shared__ int ncand, nrows;
  const int tid = threadIdx.x;
  const int lane = tid & 63;
  const int wave = tid >> 6;
  const int c = blockIdx.x;
  const int cx = c % 7, cy = (c / 7) % 7, cz = c / 49;

  // distributed zero of d_out (16 MiB across 343 blocks)
  float4* o4 = (float4*)out;
  for (int t = c * 256 + tid; t < MAXP; t += NCELL * 256)
    o4[t] = make_float4(0.f, 0.f, 0.f, 0.f);

  if (tid == 0) { ncand = 0; nrows = 0; }
  __syncthreads();

  for (int a = tid; a < NATOMS; a += 256) {
    float x = pos[3 * a], y = pos[3 * a + 1], z = pos[3 * a + 2];
    int ax = cellco(x), ay = cellco(y), az = cellco(z);
    int dx = ax - cx, dy = ay - cy, dz = az - cz;
    if (dx >= -1 && dx <= 1 && dy >= -1 && dy <= 1 && dz >= -1 && dz <= 1) {
      int p = atomicAdd(&ncand, 1);
      if (p < CANDCAP) {
        cand[p] = make_float4(x, y, z, sq3_nc(x, y, z));
        cj[p] = a;
      }
      if (dx == 0 && dy == 0 && dz == 0) {
        int q = atomicAdd(&nrows, 1);
        if (q < ROWCAP) rows[q] = a;
      }
    }
  }
  __syncthreads();

  int* rowcnt = (int*)(ws + W_ROWCNT);
  const int nc = ncand < CANDCAP ? ncand : CANDCAP;
  const int nr = nrows < ROWCAP ? nrows : ROWCAP;
  for (int ri = wave; ri < nr; ri += 4) {
    int row = rows[ri];
    float xi = pos[3 * row], yi = pos[3 * row + 1], zi = pos[3 * row + 2];
    float sqi = sq3_nc(xi, yi, zi);
    int cnt = 0;
    for (int b0 = 0; b0 < nc; b0 += 64) {       // UNIFORM trip count (G5!)
      int b = b0 + lane;
      bool v = b < nc;
      float4 p = v ? cand[b] : make_float4(1e30f, 1e30f, 1e30f, 0.f);
      int j = v ? cj[b] : -1;
      float d2 = d2_gram(xi, yi, zi, sqi, p.x, p.y, p.z, p.w);
      cnt += (v && (d2 < D2_CUT) && (j != row)) ? 1 : 0;
    }
    for (int off = 32; off > 0; off >>= 1) cnt += __shfl_down(cnt, off, 64);
    if (lane == 0) rowcnt[row] = cnt;
  }
}

// K2: exclusive scan of 8192 row counts
__global__ __launch_bounds__(1024) void nl_scan(float* __restrict__ ws) {
  const int* cnts = (const int*)(ws + W_ROWCNT);
  int* offs = (int*)(ws + W_ROWOFF);
  __shared__ int s[1024];
  const int tid = threadIdx.x;
  const int base = tid * 8;
  int local[8];
  int sum = 0;
#pragma unroll
  for (int k = 0; k < 8; ++k) { local[k] = sum; sum += cnts[base + k]; }
  s[tid] = sum;
  __syncthreads();
  for (int off = 1; off < 1024; off <<= 1) {
    int v = (tid >= off) ? s[tid - off] : 0;
    __syncthreads();
    s[tid] += v;
    __syncthreads();
  }
  int excl = (tid == 0) ? 0 : s[tid - 1];
#pragma unroll
  for (int k = 0; k < 8; ++k) offs[base + k] = excl + local[k];
}

// K3: per-cell block: regather + collect hits + rank-sort by j + ordered write
__global__ __launch_bounds__(256) void nl_write(const float* __restrict__ pos,
                                                float* __restrict__ out,
                                                const float* __restrict__ ws) {
  __shared__ float4 cand[CANDCAP];
  __shared__ int cj[CANDCAP];
  __shared__ int rows[ROWCAP];
  __shared__ int jb[4][HITCAP];
  __shared__ float db[4][HITCAP];
  __shared__ int ncand, nrows;
  const int tid = threadIdx.x;
  const int lane = tid & 63;
  const int wave = tid >> 6;
  const int c = blockIdx.x;
  const int cx = c % 7, cy = (c / 7) % 7, cz = c / 49;

  if (tid == 0) { ncand = 0; nrows = 0; }
  __syncthreads();

  for (int a = tid; a < NATOMS; a += 256) {
    float x = pos[3 * a], y = pos[3 * a + 1], z = pos[3 * a + 2];
    int ax = cellco(x), ay = cellco(y), az = cellco(z);
    int dx = ax - cx, dy = ay - cy, dz = az - cz;
    if (dx >= -1 && dx <= 1 && dy >= -1 && dy <= 1 && dz >= -1 && dz <= 1) {
      int p = atomicAdd(&ncand, 1);
      if (p < CANDCAP) {
        cand[p] = make_float4(x, y, z, sq3_nc(x, y, z));
        cj[p] = a;
      }
      if (dx == 0 && dy == 0 && dz == 0) {
        int q = atomicAdd(&nrows, 1);
        if (q < ROWCAP) rows[q] = a;
      }
    }
  }
  __syncthreads();

  const int* rowoff = (const int*)(ws + W_ROWOFF);
  const int nc = ncand < CANDCAP ? ncand : CANDCAP;
  const int nr = nrows < ROWCAP ? nrows : ROWCAP;
  for (int ri = wave; ri < nr; ri += 4) {
    int row = rows[ri];
    float xi = pos[3 * row], yi = pos[3 * row + 1], zi = pos[3 * row + 2];
    float sqi = sq3_nc(xi, yi, zi);
    int cnt = 0;
    for (int b0 = 0; b0 < nc; b0 += 64) {       // UNIFORM trip count (G5!)
      int b = b0 + lane;
      bool v = b < nc;
      float4 p = v ? cand[b] : make_float4(1e30f, 1e30f, 1e30f, 0.f);
      int j = v ? cj[b] : -1;
      float d2 = d2_gram(xi, yi, zi, sqi, p.x, p.y, p.z, p.w);
      bool pred = v && (d2 < D2_CUT) && (j != row);
      unsigned long long m = __ballot(pred ? 1 : 0);
      if (pred) {
        int ps = cnt + __popcll(m & ((1ull << lane) - 1ull));
        if (ps < HITCAP) {
          jb[wave][ps] = j;
          db[wave][ps] = sqrtf(d2_direct(xi, yi, zi, p.x, p.y, p.z));
        }
      }
      cnt += __popcll(m);
    }
    int k = cnt > HITCAP ? HITCAP : cnt;
    int base = rowoff[row];
    for (int midx = lane; midx < k; midx += 64) {
      int jm = jb[wave][midx];
      int rank = 0;
      for (int t = 0; t < k; ++t) rank += (jb[wave][t] < jm) ? 1 : 0;
      int idx = base + rank;
      if (idx < MAXP) {
        ((float2*)out)[idx] = make_float2((float)row, (float)jm);  // interleaved pair
        out[2 * MAXP + idx] = (row < jm) ? 1.0f : 0.0f;            // buffer_scales
        out[3 * MAXP + idx] = db[wave][midx];                      // ds
      }
    }
  }
}

extern "C" void kernel_launch(void* const* d_in, const int* in_sizes, int n_in,
                              void* d_out, int out_size, void* d_ws, size_t ws_size,
                              hipStream_t stream) {
  const float* pos = (const float*)d_in[0];  // float32 [8192,3]
  float* out = (float*)d_out;                // float32 [4*MAXP]
  float* ws = (float*)d_ws;

  nl_count<<<NCELL, 256, 0, stream>>>(pos, out, ws);
  nl_scan<<<1, 1024, 0, stream>>>(ws);
  nl_write<<<NCELL, 256, 0, stream>>>(pos, out, ws);
}

// Round 18
// 111.363 us; speedup vs baseline: 1.4289x; 1.4289x over previous
//
#include <hip/hip_runtime.h>

#define MAXP 1048576           // static pair bound (MAX_PAIRS)
#define NATOMS 8192
#define D2_CUT 0x1.8ffffep+4f  // fl(sqrt(s))<5  <=>  s < 25-2^-19
#define NB 64                  // x-bins; bin = clamp((int)(x*1.6), 0, 63)
#define HITCAP 192             // hits per row (mean 56, max ~100)
#define XMARGIN 5.001f         // |dx|>5.001 => true d2>25.01 => gram d2>25.007 > cut

// d_ws layout (float offsets)
#define W_BINOFF  0            // 65 ints (padded to 256)
#define W_SORTID  256          // 8192 ints
#define W_ROWCNT  8448         // 8192 ints
#define W_ROWOFF  16640        // 8192 ints
#define W_SORTPOS 24832        // float4[8192] (byte offset 99328, 16B-aligned)

__device__ __forceinline__ float sq3_nc(float x, float y, float z) {
#pragma clang fp contract(off)
  float a = x * x;
  float b = y * y;
  float c = z * z;
  return (a + b) + c;
}

// mask per _pairwise_dist: sq_i + sq_j - 2*(x @ x.T); BLAS K=3 FMA chain (bit-exact r12-r17)
__device__ __forceinline__ float d2_gram(float xi, float yi, float zi, float sqi,
                                         float xj, float yj, float zj, float sqj) {
#pragma clang fp contract(off)
  float g = xi * xj;
  g = __builtin_fmaf(yi, yj, g);
  g = __builtin_fmaf(zi, zj, g);
  float t = sqi + sqj;
  float d2 = t - 2.0f * g;
  return d2;
}

__device__ __forceinline__ float d2_direct(float xi, float yi, float zi,
                                           float xj, float yj, float zj) {
#pragma clang fp contract(off)
  float dx = xj - xi;
  float dy = yj - yi;
  float dz = zj - zi;
  float a = dx * dx;
  float b = dy * dy;
  float c = dz * dz;
  return (a + b) + c;
}

__device__ __forceinline__ int xbin(float x) {
  int b = (int)(x * 1.6f);      // monotone in x -> conservative windows
  return b < 0 ? 0 : (b > 63 ? 63 : b);
}

// K0: single block: 64-bin histogram (per-wave privatized), scan, stable-ish scatter
__global__ __launch_bounds__(1024) void nl_sort(const float* __restrict__ pos,
                                                float* __restrict__ ws) {
  __shared__ int h[16][NB];     // per-wave histograms
  __shared__ int base[16][NB];  // per-wave per-bin base
  __shared__ int cur[16][NB];   // per-wave cursors
  __shared__ int boff[NB + 1];
  const int tid = threadIdx.x;
  const int lane = tid & 63;
  const int wave = tid >> 6;
  h[wave][lane] = 0;
  cur[wave][lane] = 0;
  __syncthreads();

  float x[8], y[8], z[8];
  int bn[8];
#pragma unroll
  for (int k = 0; k < 8; ++k) {
    int a = tid + k * 1024;
    x[k] = pos[3 * a]; y[k] = pos[3 * a + 1]; z[k] = pos[3 * a + 2];
    bn[k] = xbin(x[k]);
    atomicAdd(&h[wave][bn[k]], 1);   // ~1 conflict/lane: per-wave private
  }
  __syncthreads();

  if (tid < NB) {                    // column pass: bases + totals
    int run = 0;
    for (int w = 0; w < 16; ++w) { base[w][tid] = run; run += h[w][tid]; }
    h[0][tid] = run;                 // total for bin 'tid'
  }
  __syncthreads();
  if (tid == 0) {                    // tiny serial scan over 64 bins
    int run = 0;
    for (int b = 0; b < NB; ++b) { boff[b] = run; run += h[0][b]; }
    boff[NB] = run;                  // 8192
  }
  __syncthreads();
  if (tid < NB + 1) ((int*)(ws + W_BINOFF))[tid] = boff[tid];

  int* sid = (int*)(ws + W_SORTID);
  float4* sp4 = (float4*)(ws + W_SORTPOS);
#pragma unroll
  for (int k = 0; k < 8; ++k) {
    int local = atomicAdd(&cur[wave][bn[k]], 1);
    int slot = boff[bn[k]] + base[wave][bn[k]] + local;
    sid[slot] = tid + k * 1024;
    sp4[slot] = make_float4(x[k], y[k], z[k], sq3_nc(x[k], y[k], z[k]));
  }
}

// K1: zero d_out (distributed) + count: one wave per 2 sorted rows, contiguous window
__global__ __launch_bounds__(256) void nl_count(float* __restrict__ out,
                                                float* __restrict__ ws) {
  float4* o4 = (float4*)out;
  int gt = blockIdx.x * 256 + threadIdx.x;
#pragma unroll
  for (int k = 0; k < 4; ++k)        // 1024*256*4 = 1,048,576 float4 = 16 MiB
    o4[gt + k * 262144] = make_float4(0.f, 0.f, 0.f, 0.f);

  const float4* sp4 = (const float4*)(ws + W_SORTPOS);
  const int* sid = (const int*)(ws + W_SORTID);
  const int* boff = (const int*)(ws + W_BINOFF);
  int* rowcnt = (int*)(ws + W_ROWCNT);
  const int lane = threadIdx.x & 63;
  const int wave = threadIdx.x >> 6;
  const int s = (blockIdx.x * 4 + wave) * 2;     // sorted rows s, s+1
  float4 p0 = sp4[s], p1 = sp4[s + 1];           // p0.x <= p1.x
  int r0 = sid[s], r1 = sid[s + 1];
  int lb = xbin(p0.x - XMARGIN), hb = xbin(p1.x + XMARGIN);
  int t0 = boff[lb], t1 = boff[hb + 1];
  int c0 = 0, c1 = 0;
  for (int tb = t0; tb < t1; tb += 64) {         // uniform trip count
    int t = tb + lane;
    bool v = t < t1;
    float4 q = v ? sp4[t] : make_float4(1e30f, 1e30f, 1e30f, 0.f);
    float d20 = d2_gram(p0.x, p0.y, p0.z, p0.w, q.x, q.y, q.z, q.w);
    float d21 = d2_gram(p1.x, p1.y, p1.z, p1.w, q.x, q.y, q.z, q.w);
    c0 += (v && d20 < D2_CUT) ? 1 : 0;           // self always hits -> subtract 1
    c1 += (v && d21 < D2_CUT) ? 1 : 0;
  }
  for (int off = 32; off > 0; off >>= 1) {
    c0 += __shfl_down(c0, off, 64);
    c1 += __shfl_down(c1, off, 64);
  }
  if (lane == 0) { rowcnt[r0] = c0 - 1; rowcnt[r1] = c1 - 1; }
}

// K2: exclusive scan of 8192 row counts (by original row id)
__global__ __launch_bounds__(1024) void nl_scan(float* __restrict__ ws) {
  const int* cnts = (const int*)(ws + W_ROWCNT);
  int* offs = (int*)(ws + W_ROWOFF);
  __shared__ int s[1024];
  const int tid = threadIdx.x;
  const int base = tid * 8;
  int local[8];
  int sum = 0;
#pragma unroll
  for (int k = 0; k < 8; ++k) { local[k] = sum; sum += cnts[base + k]; }
  s[tid] = sum;
  __syncthreads();
  for (int off = 1; off < 1024; off <<= 1) {
    int v = (tid >= off) ? s[tid - off] : 0;
    __syncthreads();
    s[tid] += v;
    __syncthreads();
  }
  int excl = (tid == 0) ? 0 : s[tid - 1];
#pragma unroll
  for (int k = 0; k < 8; ++k) offs[base + k] = excl + local[k];
}

// K3: collect hits for 2 sorted rows/wave, rank-sort by j, ordered write
__global__ __launch_bounds__(256) void nl_write(float* __restrict__ out,
                                                const float* __restrict__ ws) {
  __shared__ int jb[8][HITCAP];
  __shared__ float db[8][HITCAP];
  const float4* sp4 = (const float4*)(ws + W_SORTPOS);
  const int* sid = (const int*)(ws + W_SORTID);
  const int* boff = (const int*)(ws + W_BINOFF);
  const int* rowoff = (const int*)(ws + W_ROWOFF);
  const int lane = threadIdx.x & 63;
  const int wave = threadIdx.x >> 6;
  const int s = (blockIdx.x * 4 + wave) * 2;
  float4 p0 = sp4[s], p1 = sp4[s + 1];
  int r0 = sid[s], r1 = sid[s + 1];
  int lb = xbin(p0.x - XMARGIN), hb = xbin(p1.x + XMARGIN);
  int t0 = boff[lb], t1 = boff[hb + 1];
  const int w0 = wave * 2, w1 = wave * 2 + 1;
  int c0 = 0, c1 = 0;
  for (int tb = t0; tb < t1; tb += 64) {         // uniform trip count
    int t = tb + lane;
    bool v = t < t1;
    float4 q = v ? sp4[t] : make_float4(1e30f, 1e30f, 1e30f, 0.f);
    int j = v ? sid[t] : -1;
    float d20 = d2_gram(p0.x, p0.y, p0.z, p0.w, q.x, q.y, q.z, q.w);
    float d21 = d2_gram(p1.x, p1.y, p1.z, p1.w, q.x, q.y, q.z, q.w);
    bool pr0 = v && (d20 < D2_CUT) && (j != r0);
    unsigned long long m0 = __ballot(pr0 ? 1 : 0);
    if (pr0) {
      int ps = c0 + __popcll(m0 & ((1ull << lane) - 1ull));
      if (ps < HITCAP) {
        jb[w0][ps] = j;
        db[w0][ps] = sqrtf(d2_direct(p0.x, p0.y, p0.z, q.x, q.y, q.z));
      }
    }
    c0 += __popcll(m0);
    bool pr1 = v && (d21 < D2_CUT) && (j != r1);
    unsigned long long m1 = __ballot(pr1 ? 1 : 0);
    if (pr1) {
      int ps = c1 + __popcll(m1 & ((1ull << lane) - 1ull));
      if (ps < HITCAP) {
        jb[w1][ps] = j;
        db[w1][ps] = sqrtf(d2_direct(p1.x, p1.y, p1.z, q.x, q.y, q.z));
      }
    }
    c1 += __popcll(m1);
  }
  // ordered writes: rank by j (unique) restores ascending-j within each row
  int k0 = c0 > HITCAP ? HITCAP : c0;
  int b0 = rowoff[r0];
  for (int midx = lane; midx < k0; midx += 64) {
    int jm = jb[w0][midx];
    int rank = 0;
    for (int t = 0; t < k0; ++t) rank += (jb[w0][t] < jm) ? 1 : 0;
    int idx = b0 + rank;
    if (idx < MAXP) {
      ((float2*)out)[idx] = make_float2((float)r0, (float)jm);
      out[2 * MAXP + idx] = (r0 < jm) ? 1.0f : 0.0f;
      out[3 * MAXP + idx] = db[w0][midx];
    }
  }
  int k1 = c1 > HITCAP ? HITCAP : c1;
  int b1 = rowoff[r1];
  for (int midx = lane; midx < k1; midx += 64) {
    int jm = jb[w1][midx];
    int rank = 0;
    for (int t = 0; t < k1; ++t) rank += (jb[w1][t] < jm) ? 1 : 0;
    int idx = b1 + rank;
    if (idx < MAXP) {
      ((float2*)out)[idx] = make_float2((float)r1, (float)jm);
      out[2 * MAXP + idx] = (r1 < jm) ? 1.0f : 0.0f;
      out[3 * MAXP + idx] = db[w1][midx];
    }
  }
}

extern "C" void kernel_launch(void* const* d_in, const int* in_sizes, int n_in,
                              void* d_out, int out_size, void* d_ws, size_t ws_size,
                              hipStream_t stream) {
  const float* pos = (const float*)d_in[0];  // float32 [8192,3]
  float* out = (float*)d_out;                // float32 [4*MAXP]
  float* ws = (float*)d_ws;

  nl_sort<<<1, 1024, 0, stream>>>(pos, ws);
  nl_count<<<1024, 256, 0, stream>>>(out, ws);
  nl_scan<<<1, 1024, 0, stream>>>(ws);
  nl_write<<<1024, 256, 0, stream>>>(out, ws);
}

// Round 19
// 100.726 us; speedup vs baseline: 1.5798x; 1.1056x over previous
//
#include <hip/hip_runtime.h>

#define MAXP 1048576           // static pair bound (MAX_PAIRS)
#define NATOMS 8192
#define D2_CUT 0x1.8ffffep+4f  // fl(sqrt(s))<5  <=>  s < 25-2^-19
#define CINV 0.175f            // 7/40: 7^3=343 cells, width 5.714 > 5.0004 (conservative)
#define CAP 192                // max hits/row (avg 56)

// d_ws layout (float offsets); all fields fully written before read each call
#define W_CELLOFF 0            // 344 ints (padded to 512)
#define W_SORTID  512          // 8192 ints
#define W_ROWCNT  8704         // 8192 ints
#define W_ROWOFF  16896        // 8192 ints
#define W_SORTPOS 25088        // float4[8192] (byte 100352, 16B aligned)

__device__ __forceinline__ float sq3_nc(float x, float y, float z) {
#pragma clang fp contract(off)
  float a = x * x;
  float b = y * y;
  float c = z * z;
  return (a + b) + c;
}

// mask per _pairwise_dist: sq_i + sq_j - 2*(x @ x.T); BLAS K=3 FMA chain (bit-exact r12-r18)
__device__ __forceinline__ float d2_gram(float xi, float yi, float zi, float sqi,
                                         float xj, float yj, float zj, float sqj) {
#pragma clang fp contract(off)
  float g = xi * xj;
  g = __builtin_fmaf(yi, yj, g);
  g = __builtin_fmaf(zi, zj, g);
  float t = sqi + sqj;
  float d2 = t - 2.0f * g;
  return d2;
}

__device__ __forceinline__ float d2_direct(float xi, float yi, float zi,
                                           float xj, float yj, float zj) {
#pragma clang fp contract(off)
  float dx = xj - xi;
  float dy = yj - yi;
  float dz = zj - zi;
  float a = dx * dx;
  float b = dy * dy;
  float c = dz * dz;
  return (a + b) + c;
}

__device__ __forceinline__ int cellco(float v) {
  int c = (int)(v * CINV);
  return c < 0 ? 0 : (c > 6 ? 6 : c);
}

// K0: single block: bin + scan + scatter entirely in LDS (proven in r15)
__global__ __launch_bounds__(1024) void nl_prep(const float* __restrict__ pos,
                                                float* __restrict__ ws) {
  __shared__ int hcnt[343];
  __shared__ int hoff[344];
  __shared__ int hcur[343];
  __shared__ int s[512];
  const int tid = threadIdx.x;
  if (tid < 343) { hcnt[tid] = 0; hcur[tid] = 0; }
  __syncthreads();

  float x[8], y[8], z[8];
  int cl[8];
#pragma unroll
  for (int k = 0; k < 8; ++k) {
    int a = tid + k * 1024;
    x[k] = pos[3 * a]; y[k] = pos[3 * a + 1]; z[k] = pos[3 * a + 2];
    cl[k] = cellco(x[k]) + 7 * cellco(y[k]) + 49 * cellco(z[k]);
    atomicAdd(&hcnt[cl[k]], 1);
  }
  __syncthreads();

  if (tid < 512) s[tid] = (tid < 343) ? hcnt[tid] : 0;
  __syncthreads();
  for (int off = 1; off < 512; off <<= 1) {
    int v = (tid < 512 && tid >= off) ? s[tid - off] : 0;
    __syncthreads();
    if (tid < 512) s[tid] += v;
    __syncthreads();
  }
  if (tid < 343) hoff[tid] = (tid == 0) ? 0 : s[tid - 1];
  if (tid == 343) hoff[343] = NATOMS;
  __syncthreads();
  if (tid < 344) ((int*)(ws + W_CELLOFF))[tid] = hoff[tid];

  int* sortid = (int*)(ws + W_SORTID);
  float4* sortpos = (float4*)(ws + W_SORTPOS);
#pragma unroll
  for (int k = 0; k < 8; ++k) {
    int slot = hoff[cl[k]] + atomicAdd(&hcur[cl[k]], 1);
    sortid[slot] = tid + k * 1024;
    sortpos[slot] = make_float4(x[k], y[k], z[k], sq3_nc(x[k], y[k], z[k]));
  }
}

// K1: fused d_out zero + count (r14's measured-fastest hot loop, one wave/row)
__global__ __launch_bounds__(256) void nl_rowcount(const float* __restrict__ pos,
                                                   float* __restrict__ out,
                                                   float* __restrict__ ws) {
  float4* o4 = (float4*)out;
  const int b = blockIdx.x;
  o4[b * 512 + threadIdx.x] = make_float4(0.f, 0.f, 0.f, 0.f);
  o4[b * 512 + 256 + threadIdx.x] = make_float4(0.f, 0.f, 0.f, 0.f);

  const int* celloff = (const int*)(ws + W_CELLOFF);
  const int* sortid = (const int*)(ws + W_SORTID);
  const float4* sortpos = (const float4*)(ws + W_SORTPOS);
  int* rowcnt = (int*)(ws + W_ROWCNT);
  const int lane = threadIdx.x & 63;
  const int wave = threadIdx.x >> 6;
  const int row = b * 4 + wave;
  float xi = pos[3 * row], yi = pos[3 * row + 1], zi = pos[3 * row + 2];
  float sqi = sq3_nc(xi, yi, zi);
  int cx = cellco(xi), cy = cellco(yi), cz = cellco(zi);
  int x0 = max(cx - 1, 0), x1 = min(cx + 1, 6);
  int y0 = max(cy - 1, 0), y1 = min(cy + 1, 6);
  int z0 = max(cz - 1, 0), z1 = min(cz + 1, 6);
  int cnt = 0;
  for (int icz = z0; icz <= z1; ++icz)
    for (int icy = y0; icy <= y1; ++icy) {
      int cb = 7 * icy + 49 * icz;
      int st = celloff[cb + x0];
      int en = celloff[cb + x1 + 1];
      for (int bb = st; bb < en; bb += 64) {
        int t = bb + lane;
        bool v = t < en;
        float4 p = v ? sortpos[t] : make_float4(1e30f, 1e30f, 1e30f, 0.f);
        int j = v ? sortid[t] : -1;
        float d2 = d2_gram(xi, yi, zi, sqi, p.x, p.y, p.z, p.w);
        cnt += (v && (d2 < D2_CUT) && (j != row)) ? 1 : 0;
      }
    }
  for (int off = 32; off > 0; off >>= 1) cnt += __shfl_down(cnt, off, 64);
  if (lane == 0) rowcnt[row] = cnt;
}

// K2: exclusive scan of 8192 row counts
__global__ __launch_bounds__(1024) void nl_rowscan(float* __restrict__ ws) {
  const int* cnts = (const int*)(ws + W_ROWCNT);
  int* offs = (int*)(ws + W_ROWOFF);
  __shared__ int s[1024];
  const int tid = threadIdx.x;
  const int base = tid * 8;
  int local[8];
  int sum = 0;
#pragma unroll
  for (int k = 0; k < 8; ++k) { local[k] = sum; sum += cnts[base + k]; }
  s[tid] = sum;
  __syncthreads();
  for (int off = 1; off < 1024; off <<= 1) {
    int v = (tid >= off) ? s[tid - off] : 0;
    __syncthreads();
    s[tid] += v;
    __syncthreads();
  }
  int excl = (tid == 0) ? 0 : s[tid - 1];
#pragma unroll
  for (int k = 0; k < 8; ++k) offs[base + k] = excl + local[k];
}

// K3: collect hits (r14 hot loop) + rank-sort by j + ordered write
__global__ __launch_bounds__(256) void nl_rowwrite(const float* __restrict__ pos,
                                                   float* __restrict__ out,
                                                   const float* __restrict__ ws) {
  const int* celloff = (const int*)(ws + W_CELLOFF);
  const int* sortid = (const int*)(ws + W_SORTID);
  const float4* sortpos = (const float4*)(ws + W_SORTPOS);
  const int* rowoff = (const int*)(ws + W_ROWOFF);
  __shared__ int jb[4][CAP];
  __shared__ float db[4][CAP];
  const int lane = threadIdx.x & 63;
  const int wave = threadIdx.x >> 6;
  const int row = blockIdx.x * 4 + wave;
  float xi = pos[3 * row], yi = pos[3 * row + 1], zi = pos[3 * row + 2];
  float sqi = sq3_nc(xi, yi, zi);
  int cx = cellco(xi), cy = cellco(yi), cz = cellco(zi);
  int x0 = max(cx - 1, 0), x1 = min(cx + 1, 6);
  int y0 = max(cy - 1, 0), y1 = min(cy + 1, 6);
  int z0 = max(cz - 1, 0), z1 = min(cz + 1, 6);
  int cnt = 0;
  for (int icz = z0; icz <= z1; ++icz)
    for (int icy = y0; icy <= y1; ++icy) {
      int cb = 7 * icy + 49 * icz;
      int st = celloff[cb + x0];
      int en = celloff[cb + x1 + 1];
      for (int bb = st; bb < en; bb += 64) {
        int t = bb + lane;
        bool v = t < en;
        float4 p = v ? sortpos[t] : make_float4(1e30f, 1e30f, 1e30f, 0.f);
        int j = v ? sortid[t] : -1;
        float d2 = d2_gram(xi, yi, zi, sqi, p.x, p.y, p.z, p.w);
        bool pred = v && (d2 < D2_CUT) && (j != row);
        unsigned long long m = __ballot(pred ? 1 : 0);
        if (pred) {
          int ps = cnt + __popcll(m & ((1ull << lane) - 1ull));
          if (ps < CAP) {
            jb[wave][ps] = j;
            db[wave][ps] = sqrtf(d2_direct(xi, yi, zi, p.x, p.y, p.z));
          }
        }
        cnt += __popcll(m);
      }
    }
  int k = cnt > CAP ? CAP : cnt;
  int base = rowoff[row];
  for (int midx = lane; midx < k; midx += 64) {
    int jm = jb[wave][midx];
    int rank = 0;
    for (int t = 0; t < k; ++t) rank += (jb[wave][t] < jm) ? 1 : 0;
    int idx = base + rank;
    if (idx < MAXP) {
      ((float2*)out)[idx] = make_float2((float)row, (float)jm);  // interleaved pair
      out[2 * MAXP + idx] = (row < jm) ? 1.0f : 0.0f;            // buffer_scales
      out[3 * MAXP + idx] = db[wave][midx];                      // ds
    }
  }
}

extern "C" void kernel_launch(void* const* d_in, const int* in_sizes, int n_in,
                              void* d_out, int out_size, void* d_ws, size_t ws_size,
                              hipStream_t stream) {
  const float* pos = (const float*)d_in[0];  // float32 [8192,3]
  float* out = (float*)d_out;                // float32 [4*MAXP]
  float* ws = (float*)d_ws;

  nl_prep<<<1, 1024, 0, stream>>>(pos, ws);
  nl_rowcount<<<NATOMS / 4, 256, 0, stream>>>(pos, out, ws);
  nl_rowscan<<<1, 1024, 0, stream>>>(ws);
  nl_rowwrite<<<NATOMS / 4, 256, 0, stream>>>(pos, out, ws);
}